// Round 14
// baseline (296613.794 us; speedup 1.0000x reference)
//
#include <hip/hip_runtime.h>
#include <math.h>

#define BATCH 1024
#define SEQ   256
#define UNITS 256
#define NC    128

typedef __attribute__((ext_vector_type(8))) short  short8;   // 8 bf16 = 4 regs
typedef __attribute__((ext_vector_type(4))) float  float4v;  // MFMA C/D
typedef __attribute__((ext_vector_type(4))) unsigned int u32x4;
typedef unsigned long long u64;
typedef unsigned int       u32;
typedef unsigned short     u16;

// Gate math (validated r1-r12: absmax <= 6.1e-5 vs 1.72e-4 threshold)
__device__ __forceinline__ float sigf(float x)  { return 1.f / (1.f + __expf(-x)); }
__device__ __forceinline__ float tanhf_(float x){ return 1.f - 2.f / (1.f + __expf(2.f * x)); }

__device__ __forceinline__ u16 bf16rne(float f) {
    unsigned u = __float_as_uint(f);
    return (u16)((u + 0x7fffu + ((u >> 16) & 1u)) >> 16);
}
__device__ __forceinline__ float bf16tof(u16 s) {
    return __uint_as_float(((unsigned)s) << 16);
}

// ---------------------------------------------------------------------------
// prep: R0t/R1t[col][k] bf16 split (col = g*256+u, r4-verified layout);
//       Wkb[ch][u*4+g] = Wk + bias; H01A zeroed; flags+claim zeroed.
__global__ __launch_bounds__(256) void prep(
    const float* __restrict__ R, const float* __restrict__ Wk,
    const float* __restrict__ bias,
    u16* __restrict__ R0t, u16* __restrict__ R1t,
    float* __restrict__ Wkb, u32* __restrict__ H01A, u32* __restrict__ flags)
{
    int i = blockIdx.x * 256 + threadIdx.x;    // 0..262143
    int col = i >> 8, k = i & 255;
    float v = R[k * 1024 + col];
    u16 r0 = bf16rne(v);
    R0t[i] = r0;
    R1t[i] = bf16rne(v - bf16tof(r0));
    H01A[i] = 0u;                              // h_0 = 0 (packed)
    if (i < NC * 1024) {
        int r = i & 1023;
        int u = r >> 2, g = r & 3;
        int src = (g << 8) + u;
        Wkb[i] = Wk[(i >> 10) * 1024 + src] + bias[src];
    }
    if (i < 4352) flags[i] = 0u;               // 4096 flags + claim region
}

// ---------------------------------------------------------------------------
// Persistent LSTM with XCD-LOCAL sync domains (r13 design, r14 launch fix).
// r8-r11 measured ~3.5us/step for h exchange through the MALL (the only
// architecturally cross-XCD-coherent point). Here each row's 4 blocks are
// guaranteed co-XCD by construction: blocks read their physical XCD id
// (s_getreg HW_REG_XCC_ID, HW-verified m09) and claim a slot from their own
// XCD's pool. Pigeonhole: 96.9KB LDS/block forces 1 block/CU; persistent
// completion requires all 256 blocks co-resident (r8-proven) -> exactly one
// block per CU -> exactly 32 per XCD -> every XCD pool fills to 32. No
// dispatch-order assumption.
// h exchange: plain stores (write-through L1 -> XCD L2), vmcnt drain via
// __syncthreads (r8-validated), plain flag store; consumers poll + bulk-load
// with sc0 (L1-bypass) reads of the same XCD L2 (~200cyc vs ~2000+ MALL).
// Zero agent-scope ops in the t-loop. ALL spins bounded (20000 iters): a
// wrong placement model produces a finite wrong answer, never a hang.
// Compute = r8's validated structure (256-AGPR B, 3-product, hazard barrier).
__global__ __launch_bounds__(256, 1) void lstm_persist(
    const u16* __restrict__ R0t, const u16* __restrict__ R1t,
    const float* __restrict__ Wkb, const int* __restrict__ inp,
    u32* __restrict__ H01A, u32* __restrict__ H01B, u32* __restrict__ flags)
{
    extern __shared__ u32 lds_pad[];        // +80KB dynamic: forces 1 block/CU
    __shared__ u32 L[2][16 * 132];          // [plane][batch*132 + u32col]
    __shared__ u32 slot_s;

    const int tid  = threadIdx.x;
    const int lane = tid & 63;
    const int wv   = tid >> 6;              // 0..3
    const int nl   = lane & 15;
    const int quad = lane >> 4;

    // --- XCD-local slot claim (once per launch; prep re-zeroes counters) ---
    u32 xcd;
    asm("s_getreg_b32 %0, hwreg(HW_REG_XCC_ID)" : "=s"(xcd));
    xcd &= 7u;
    if (tid == 0) {
        slot_s = __hip_atomic_fetch_add(&flags[4096 + (xcd << 4)], 1u,
                                        __ATOMIC_RELAXED, __HIP_MEMORY_SCOPE_AGENT);
    }
    __syncthreads();
    const int slot = (int)(slot_s & 31);            // wrap: no OOB even if claim off
    if (slot_s == 0xfffffffeu) lds_pad[0] = 1u;     // keep dynamic LDS alive
    const int row = ((int)xcd << 3) + (slot >> 2);  // 0..63 (16-batch row)
    const int g4  = slot & 3;                       // 64-unit group 0..3
    const int u   = (g4 << 6) + (wv << 4) + nl;     // lane's unit
    const int bm  = row << 4;
    const int be  = bm + (quad << 2);               // lane's 4-batch base

    // --- B-frags (r4-verified layout) -> 256 AGPRs, pinned (r8) ---
    short8 B0[4][8], B1[4][8];
#pragma unroll
    for (int g = 0; g < 4; g++)
#pragma unroll
        for (int kt = 0; kt < 8; kt++) {
            const int idx = ((g << 8) + u) * 256 + (kt << 5) + (quad << 3);
            B0[g][kt] = *(const short8*)&R0t[idx];
            B1[g][kt] = *(const short8*)&R1t[idx];
        }
#pragma unroll
    for (int g = 0; g < 4; g++)
#pragma unroll
        for (int kt = 0; kt < 8; kt++) {
            asm volatile("" : "+a"(B0[g][kt]));
            asm volatile("" : "+a"(B1[g][kt]));
        }

    float c[4] = {0.f, 0.f, 0.f, 0.f};
    const int rr  = tid >> 4;               // staging: batch row
    const int cpb = (tid & 15) << 3;        // staging: u32-col base

    for (int t = 0; t < SEQ; t++) {
        const u32* Hin  = (t & 1) ? H01B : H01A;
        u32*       Hout = (t & 1) ? H01A : H01B;

        // inp + Wkb gathers (read-only, L1/L2-hot), issued early.
        int ch[4];
#pragma unroll
        for (int r = 0; r < 4; r++) ch[r] = inp[(be + r) * SEQ + t];
        float4v wk[4];
#pragma unroll
        for (int r = 0; r < 4; r++)
            wk[r] = *(const float4v*)&Wkb[(ch[r] << 10) + (u << 2)];

        // --- Wait: all 4 blocks of this row published h_t (XCD-L2 poll,
        // BOUNDED: legit wait <= ~1us; guard exit -> finite wrong answer) ---
        if (t) {
            if (tid < 4) {
                const u32* fp = &flags[((row << 2) + tid) << 4];
                int guard = 20000;
                u32 v;
                do {
                    asm volatile("global_load_dword %0, %1, off sc0\n\t"
                                 "s_waitcnt vmcnt(0)"
                                 : "=v"(v) : "v"(fp) : "memory");
                } while (v < (u32)t && --guard);
            }
            __syncthreads();
        }

        // --- Bulk h load: 16KB row slice, sc0 (L1-bypass, XCD-L2 read) ---
        u32 w[16];
        {
            const u32* p = Hin + (row << 12) + (tid << 4);
            u32x4 qa, qb, qc, qd;
            asm volatile("global_load_dwordx4 %0, %4, off sc0\n\t"
                         "global_load_dwordx4 %1, %5, off sc0\n\t"
                         "global_load_dwordx4 %2, %6, off sc0\n\t"
                         "global_load_dwordx4 %3, %7, off sc0\n\t"
                         "s_waitcnt vmcnt(0)"
                         : "=v"(qa), "=v"(qb), "=v"(qc), "=v"(qd)
                         : "v"(p), "v"(p + 4), "v"(p + 8), "v"(p + 12)
                         : "memory");
            *(u32x4*)&w[0]  = qa; *(u32x4*)&w[4]  = qb;
            *(u32x4*)&w[8]  = qc; *(u32x4*)&w[12] = qd;
        }
        // Unpack packed h -> bf16-split LDS planes (r8 layout).
#pragma unroll
        for (int i = 0; i < 8; i++) {
            u32 w0 = w[2 * i], w1 = w[2 * i + 1];
            L[0][rr * 132 + cpb + i] = (w0 & 0xffffu) | (w1 << 16);
            L[1][rr * 132 + cpb + i] = (w0 >> 16) | (w1 & 0xffff0000u);
        }
        __syncthreads();

        // --- MFMA: A from LDS (shared by 4 waves), B from AGPRs ---
        float4v acc[4];
#pragma unroll
        for (int kt = 0; kt < 8; kt++) {
            short8 a0 = *(const short8*)&L[0][nl * 132 + (kt << 4) + (quad << 2)];
            short8 a1 = *(const short8*)&L[1][nl * 132 + (kt << 4) + (quad << 2)];
            if (kt == 0) {
#pragma unroll
                for (int g = 0; g < 4; g++) {
                    asm volatile("v_mfma_f32_16x16x32_bf16 %0, %1, %2, 0"
                                 : "=v"(acc[g]) : "v"(a0), "a"(B0[g][0]));
                    asm volatile("v_mfma_f32_16x16x32_bf16 %0, %1, %2, %0"
                                 : "+v"(acc[g]) : "v"(a1), "a"(B0[g][0]));
                    asm volatile("v_mfma_f32_16x16x32_bf16 %0, %1, %2, %0"
                                 : "+v"(acc[g]) : "v"(a0), "a"(B1[g][0]));
                }
            } else {
#pragma unroll
                for (int g = 0; g < 4; g++) {
                    asm volatile("v_mfma_f32_16x16x32_bf16 %0, %1, %2, %0"
                                 : "+v"(acc[g]) : "v"(a0), "a"(B0[g][kt]));
                    asm volatile("v_mfma_f32_16x16x32_bf16 %0, %1, %2, %0"
                                 : "+v"(acc[g]) : "v"(a1), "a"(B0[g][kt]));
                    asm volatile("v_mfma_f32_16x16x32_bf16 %0, %1, %2, %0"
                                 : "+v"(acc[g]) : "v"(a0), "a"(B1[g][kt]));
                }
            }
        }
        // Sound hazard barrier (r10-validated): acc is an operand.
        asm volatile("s_nop 7\n\ts_nop 7\n\ts_nop 7"
                     : "+v"(acc[0]), "+v"(acc[1]), "+v"(acc[2]), "+v"(acc[3]));

        // --- Epilogue: plain h stores (write-through -> XCD L2) ---
#pragma unroll
        for (int r = 0; r < 4; r++) {
            float zi = acc[0][r] + wk[r].x;
            float zf = acc[1][r] + wk[r].y;
            float zg = acc[2][r] + wk[r].z;
            float zo = acc[3][r] + wk[r].w;
            float ig = sigf(zi), fg = sigf(zf), gg = tanhf_(zg), og = sigf(zo);
            float cn = fg * c[r] + ig * gg;
            c[r] = cn;
            float hv = og * tanhf_(cn);
            u16 h0 = bf16rne(hv);
            u16 h1 = bf16rne(hv - bf16tof(h0));
            Hout[(be + r) * 256 + u] = (u32)h0 | ((u32)h1 << 16);
        }

        // --- Publish: barrier drains every wave's vmcnt (stores acked at
        // XCD L2, r8-validated), then ONE plain flag store (same L2). ---
        if (t != SEQ - 1) {
            __syncthreads();
            if (tid == 0) {
                u32* fp = &flags[((row << 2) + g4) << 4];
                u32 val = (u32)(t + 1);
                asm volatile("global_store_dword %0, %1, off"
                             :: "v"(fp), "v"(val) : "memory");
            }
        }
    }
}

// ---------------------------------------------------------------------------
// logits = h_last @ dense_w + dense_b ; softmax. h unpacked = lo + hi bf16.
__global__ __launch_bounds__(128) void dense_softmax(
    const u32* __restrict__ H01, const float* __restrict__ W,
    const float* __restrict__ b, float* __restrict__ out)
{
    __shared__ float hsr[UNITS];
    __shared__ float red[NC];
    const int bq = blockIdx.x;
    const int n  = threadIdx.x;

    u32 v0 = H01[bq * 256 + n];
    u32 v1 = H01[bq * 256 + n + 128];
    hsr[n]       = bf16tof((u16)(v0 & 0xffffu)) + bf16tof((u16)(v0 >> 16));
    hsr[n + 128] = bf16tof((u16)(v1 & 0xffffu)) + bf16tof((u16)(v1 >> 16));
    __syncthreads();

    float acc = b[n];
#pragma unroll 8
    for (int k = 0; k < UNITS; k++) acc += hsr[k] * W[k * NC + n];

    red[n] = acc;
    __syncthreads();
    for (int s = 64; s > 0; s >>= 1) {
        if (n < s) red[n] = fmaxf(red[n], red[n + s]);
        __syncthreads();
    }
    float m = red[0];
    __syncthreads();

    float e = __expf(acc - m);
    red[n] = e;
    __syncthreads();
    for (int s = 64; s > 0; s >>= 1) {
        if (n < s) red[n] = red[n] + red[n + s];
        __syncthreads();
    }
    out[bq * NC + n] = e / red[0];
}

// ---------------------------------------------------------------------------
extern "C" void kernel_launch(void* const* d_in, const int* in_sizes, int n_in,
                              void* d_out, int out_size, void* d_ws, size_t ws_size,
                              hipStream_t stream)
{
    const int*   inp  = (const int*)d_in[0];    // [1024][256]
    const float* Wk   = (const float*)d_in[1];  // [128][1024]
    const float* R    = (const float*)d_in[2];  // [256][1024]
    const float* bias = (const float*)d_in[3];  // [1024]
    const float* Wd   = (const float*)d_in[4];  // [256][128]
    const float* bd   = (const float*)d_in[5];  // [128]
    float* out = (float*)d_out;

    // ws: R0t|R1t (512KB ea) | Wkb (512KB) | H01A|H01B (1MB ea) | flags+claim
    u16*   R0t  = (u16*)d_ws;
    u16*   R1t  = R0t + 262144;
    float* Wkb  = (float*)(R1t + 262144);
    u32*   H01A = (u32*)(Wkb + 131072);
    u32*   H01B = H01A + 262144;
    u32*   flags = H01B + 262144;

    prep<<<dim3(1024), dim3(256), 0, stream>>>(R, Wk, bias, R0t, R1t, Wkb, H01A, flags);

    // r13 FAILED HERE: 80KB dynamic LDS exceeds HIP's 64KB default cap ->
    // launch error. Opt in first (host-side attribute, graph-capture-safe,
    // idempotent). 16.9KB static + 80KB dynamic = 96.9KB > 160/2 KB -> the
    // HW cannot co-locate two blocks on one CU -> 1 block/CU guaranteed.
    (void)hipFuncSetAttribute((const void*)lstm_persist,
                              hipFuncAttributeMaxDynamicSharedMemorySize,
                              80 * 1024);
    lstm_persist<<<dim3(256), dim3(256), 80 * 1024, stream>>>(
        R0t, R1t, Wkb, inp, H01A, H01B, flags);

    // t=255 (odd) wrote H01A
    dense_softmax<<<dim3(BATCH), dim3(128), 0, stream>>>(H01A, Wd, bd, out);
}